// Round 1
// baseline (1355.791 us; speedup 1.0000x reference)
//
#include <hip/hip_runtime.h>

// Problem constants
#define BATCH 2
#define PLANES 3
#define CP 32           // channels per plane
#define HH 256
#define WW 256
#define HWSZ 65536      // HH*WW
#define HID 64
#define NOUT 33
#define NPTS_PER_B 524288   // VV*S = 16384*32 = 2^19
#define NPTS_TOTAL 1048576  // BATCH * NPTS_PER_B

// ---------------------------------------------------------------------------
// Kernel 1: transpose triplane (B, 96, H, W) -> ws (B*3, H*W, 32)
// so one bilinear corner = 32 contiguous floats (128 B, line-aligned).
// ---------------------------------------------------------------------------
__global__ __launch_bounds__(256) void transpose_k(const float* __restrict__ tp,
                                                   float* __restrict__ out) {
    int idx = blockIdx.x * 256 + threadIdx.x;   // 0 .. B*3*HWSZ-1 (393216)
    int bp = idx >> 16;                         // 0..5
    int yx = idx & 65535;
    int b = bp / 3, p = bp - 3 * b;
    const float* src = tp + (((size_t)(b * 96 + p * 32)) << 16) + yx;
    float4* dst = (float4*)(out + ((size_t)idx << 5));
    float v[32];
#pragma unroll
    for (int c = 0; c < 32; ++c) v[c] = src[(size_t)c << 16];
#pragma unroll
    for (int i = 0; i < 8; ++i)
        dst[i] = make_float4(v[4 * i], v[4 * i + 1], v[4 * i + 2], v[4 * i + 3]);
}

// ---------------------------------------------------------------------------
// Kernel 2: fused grid_sample (3 planes) + MLP 32->64->64->33 per point.
// VEC=true : planes is the transposed layout in ws, gather via float4.
// VEC=false: planes is original triplane layout, scalar gather (fallback).
// ---------------------------------------------------------------------------
template <bool VEC>
__global__ __launch_bounds__(256) void fused_k(const float* __restrict__ planes,
                                               const float* __restrict__ points,
                                               const float* __restrict__ W0,
                                               const float* __restrict__ b0,
                                               const float* __restrict__ W1,
                                               const float* __restrict__ b1,
                                               const float* __restrict__ W2,
                                               const float* __restrict__ b2,
                                               float* __restrict__ out) {
    __shared__ __align__(16) float sW0[CP * HID];     //  8 KB
    __shared__ __align__(16) float sW1[HID * HID];    // 16 KB
    __shared__ __align__(16) float sW2[HID * 36];     //  9 KB (33 padded to 36)
    __shared__ __align__(16) float sB0[HID];
    __shared__ __align__(16) float sB1[HID];
    __shared__ __align__(16) float sB2[36];

    const int tid = threadIdx.x;
    for (int i = tid; i < CP * HID; i += 256) sW0[i] = W0[i];
    for (int i = tid; i < HID * HID; i += 256) sW1[i] = W1[i];
    for (int i = tid; i < HID * 36; i += 256) {
        int r = i / 36, c = i - 36 * r;
        sW2[i] = (c < NOUT) ? W2[r * NOUT + c] : 0.f;
    }
    if (tid < HID) { sB0[tid] = b0[tid]; sB1[tid] = b1[tid]; }
    if (tid < 36) sB2[tid] = (tid < NOUT) ? b2[tid] : 0.f;
    __syncthreads();

    const int pgl = blockIdx.x * 256 + tid;   // < NPTS_TOTAL
    const int b = pgl >> 19;                  // NPTS_PER_B = 2^19
    const float px = points[(size_t)pgl * 3 + 0];
    const float py = points[(size_t)pgl * 3 + 1];
    const float pz = points[(size_t)pgl * 3 + 2];

    float feat[CP];
#pragma unroll
    for (int c = 0; c < CP; ++c) feat[c] = 0.f;

#pragma unroll
    for (int p = 0; p < PLANES; ++p) {
        const float gx = (p == 2) ? py : px;
        const float gy = (p == 0) ? py : pz;
        const float x = (gx + 1.0f) * 128.0f - 0.5f;
        const float y = (gy + 1.0f) * 128.0f - 0.5f;
        const float xf = floorf(x), yf = floorf(y);
        const float wx = x - xf, wy = y - yf;
        const int ix0 = (int)xf, iy0 = (int)yf;

        const float* pb = VEC
            ? planes + (((size_t)(b * 3 + p)) << 16) * 32
            : planes + (((size_t)(b * 96 + p * 32)) << 16);

        auto corner = [&](int ix, int iy, float w) {
            const bool v = (ix >= 0) & (ix < WW) & (iy >= 0) & (iy < HH);
            w = v ? w : 0.f;
            const int ixc = min(max(ix, 0), WW - 1);
            const int iyc = min(max(iy, 0), HH - 1);
            const int yx = (iyc << 8) | ixc;
            if (VEC) {
                const float4* src = (const float4*)(pb + ((size_t)yx << 5));
#pragma unroll
                for (int i = 0; i < 8; ++i) {
                    float4 val = src[i];
                    feat[4 * i + 0] = fmaf(w, val.x, feat[4 * i + 0]);
                    feat[4 * i + 1] = fmaf(w, val.y, feat[4 * i + 1]);
                    feat[4 * i + 2] = fmaf(w, val.z, feat[4 * i + 2]);
                    feat[4 * i + 3] = fmaf(w, val.w, feat[4 * i + 3]);
                }
            } else {
                const float* src = pb + yx;
#pragma unroll
                for (int c = 0; c < CP; ++c)
                    feat[c] = fmaf(w, src[(size_t)c << 16], feat[c]);
            }
        };
        corner(ix0,     iy0,     (1.f - wx) * (1.f - wy));
        corner(ix0 + 1, iy0,     wx * (1.f - wy));
        corner(ix0,     iy0 + 1, (1.f - wx) * wy);
        corner(ix0 + 1, iy0 + 1, wx * wy);
    }

    // ---- layer 0: 32 -> 64, leaky ----
    float h0[HID];
#pragma unroll
    for (int j = 0; j < HID; ++j) h0[j] = sB0[j];
    for (int k = 0; k < CP; ++k) {
        const float f = feat[k];
        const float4* row = (const float4*)(sW0 + k * HID);
#pragma unroll
        for (int j4 = 0; j4 < HID / 4; ++j4) {
            float4 w = row[j4];
            h0[4 * j4 + 0] = fmaf(f, w.x, h0[4 * j4 + 0]);
            h0[4 * j4 + 1] = fmaf(f, w.y, h0[4 * j4 + 1]);
            h0[4 * j4 + 2] = fmaf(f, w.z, h0[4 * j4 + 2]);
            h0[4 * j4 + 3] = fmaf(f, w.w, h0[4 * j4 + 3]);
        }
    }
#pragma unroll
    for (int j = 0; j < HID; ++j) h0[j] = (h0[j] >= 0.f) ? h0[j] : 0.01f * h0[j];

    // ---- layer 1: 64 -> 64, leaky ----
    float h1[HID];
#pragma unroll
    for (int j = 0; j < HID; ++j) h1[j] = sB1[j];
    for (int k = 0; k < HID; ++k) {
        const float f = h0[k];
        const float4* row = (const float4*)(sW1 + k * HID);
#pragma unroll
        for (int j4 = 0; j4 < HID / 4; ++j4) {
            float4 w = row[j4];
            h1[4 * j4 + 0] = fmaf(f, w.x, h1[4 * j4 + 0]);
            h1[4 * j4 + 1] = fmaf(f, w.y, h1[4 * j4 + 1]);
            h1[4 * j4 + 2] = fmaf(f, w.z, h1[4 * j4 + 2]);
            h1[4 * j4 + 3] = fmaf(f, w.w, h1[4 * j4 + 3]);
        }
    }
#pragma unroll
    for (int j = 0; j < HID; ++j) h1[j] = (h1[j] >= 0.f) ? h1[j] : 0.01f * h1[j];

    // ---- layer 2: 64 -> 33 (padded to 36) ----
    float o[36];
#pragma unroll
    for (int j = 0; j < 36; ++j) o[j] = sB2[j];
    for (int k = 0; k < HID; ++k) {
        const float f = h1[k];
        const float4* row = (const float4*)(sW2 + k * 36);
#pragma unroll
        for (int j4 = 0; j4 < 9; ++j4) {
            float4 w = row[j4];
            o[4 * j4 + 0] = fmaf(f, w.x, o[4 * j4 + 0]);
            o[4 * j4 + 1] = fmaf(f, w.y, o[4 * j4 + 1]);
            o[4 * j4 + 2] = fmaf(f, w.z, o[4 * j4 + 2]);
            o[4 * j4 + 3] = fmaf(f, w.w, o[4 * j4 + 3]);
        }
    }

    float* op = out + (size_t)pgl * NOUT;
#pragma unroll
    for (int j = 0; j < NOUT; ++j) op[j] = o[j];
}

// ---------------------------------------------------------------------------
extern "C" void kernel_launch(void* const* d_in, const int* in_sizes, int n_in,
                              void* d_out, int out_size, void* d_ws, size_t ws_size,
                              hipStream_t stream) {
    const float* triplane = (const float*)d_in[0];
    const float* points   = (const float*)d_in[1];
    const float* W0 = (const float*)d_in[2];
    const float* b0 = (const float*)d_in[3];
    const float* W1 = (const float*)d_in[4];
    const float* b1 = (const float*)d_in[5];
    const float* W2 = (const float*)d_in[6];
    const float* b2 = (const float*)d_in[7];
    float* out = (float*)d_out;

    const size_t need = (size_t)BATCH * PLANES * HWSZ * CP * sizeof(float); // 50.3 MB

    if (d_ws != nullptr && ws_size >= need) {
        float* tws = (float*)d_ws;
        transpose_k<<<(BATCH * PLANES * HWSZ) / 256, 256, 0, stream>>>(triplane, tws);
        fused_k<true><<<NPTS_TOTAL / 256, 256, 0, stream>>>(
            tws, points, W0, b0, W1, b1, W2, b2, out);
    } else {
        fused_k<false><<<NPTS_TOTAL / 256, 256, 0, stream>>>(
            triplane, points, W0, b0, W1, b1, W2, b2, out);
    }
}

// Round 2
// 726.994 us; speedup vs baseline: 1.8649x; 1.8649x over previous
//
#include <hip/hip_runtime.h>

// Problem constants
#define BATCH 2
#define PLANES 3
#define CP 32           // channels per plane
#define HH 256
#define WW 256
#define HWSZ 65536      // HH*WW
#define HID 64
#define NOUT 33
#define NPTS_PER_B 524288
#define NPTS_TOTAL 1048576
#define TILE 256        // points per block in fused2_k

typedef unsigned int u32;
typedef unsigned short u16;

static __device__ __forceinline__ u16 f2bf(float f) {
    u32 u = __float_as_uint(f);
    u32 r = (u + 0x7fffu + ((u >> 16) & 1u)) >> 16;  // RNE
    return (u16)r;
}

// ---------------------------------------------------------------------------
// Kernel 1: transpose triplane (B, 96, H, W) fp32 -> ws (B*3, H*W, 32) bf16.
// One bilinear corner = 32 contiguous bf16 = 64 B.
// ---------------------------------------------------------------------------
__global__ __launch_bounds__(256) void transpose_bf16_k(const float* __restrict__ tp,
                                                        u16* __restrict__ out) {
    int idx = blockIdx.x * 256 + threadIdx.x;   // 0 .. 393215
    int bp = idx >> 16;                         // 0..5
    int yx = idx & 65535;
    int b = bp / 3, p = bp - 3 * b;
    const float* src = tp + (((size_t)(b * 96 + p * 32)) << 16) + yx;
    u16 v[32];
#pragma unroll
    for (int c = 0; c < 32; ++c) v[c] = f2bf(src[(size_t)c << 16]);
    uint4* dst = (uint4*)(out + ((size_t)idx << 5));
#pragma unroll
    for (int i = 0; i < 4; ++i) {
        uint4 w;
        w.x = (u32)v[8 * i + 0] | ((u32)v[8 * i + 1] << 16);
        w.y = (u32)v[8 * i + 2] | ((u32)v[8 * i + 3] << 16);
        w.z = (u32)v[8 * i + 4] | ((u32)v[8 * i + 5] << 16);
        w.w = (u32)v[8 * i + 6] | ((u32)v[8 * i + 7] << 16);
        dst[i] = w;
    }
}

// ---------------------------------------------------------------------------
// Kernel 2: quad-cooperative gather (bf16 planes) + thread-per-point MLP.
// Weights read from global with uniform addresses (compiler -> s_load/K$).
// ---------------------------------------------------------------------------
__global__ __launch_bounds__(256) void fused2_k(const u16* __restrict__ planes,
                                                const float* __restrict__ points,
                                                const float* __restrict__ W0,
                                                const float* __restrict__ b0,
                                                const float* __restrict__ W1,
                                                const float* __restrict__ b1,
                                                const float* __restrict__ W2,
                                                const float* __restrict__ b2,
                                                float* __restrict__ out) {
    __shared__ __align__(16) float sPts[TILE * 3];    //  3 KB
    __shared__ __align__(16) float sFeat[TILE * 33];  // 33.8 KB (stride 33: conflict-free)

    const int tid = threadIdx.x;
    const int blockBase = blockIdx.x * TILE;
    const int b = blockIdx.x >> 11;  // 2048 blocks per batch (TILE*2048 = 2^19)

    // stage this tile's points (fully coalesced)
    const float* psrc = points + (size_t)blockBase * 3;
#pragma unroll
    for (int i = 0; i < 3; ++i) sPts[tid + 256 * i] = psrc[tid + 256 * i];
    __syncthreads();

    // ---- Phase A: gather. 1024 quad-tasks (point, 8-channel chunk). ----
#pragma unroll
    for (int i = 0; i < 4; ++i) {
        const int task = i * 256 + tid;
        const int pt = task >> 2;      // 0..255
        const int q  = task & 3;       // 8-channel chunk
        const float px = sPts[pt * 3 + 0];
        const float py = sPts[pt * 3 + 1];
        const float pz = sPts[pt * 3 + 2];

        float acc[8];
#pragma unroll
        for (int j = 0; j < 8; ++j) acc[j] = 0.f;

#pragma unroll
        for (int p = 0; p < PLANES; ++p) {
            const float gx = (p == 2) ? py : px;
            const float gy = (p == 0) ? py : pz;
            const float x = (gx + 1.0f) * 128.0f - 0.5f;
            const float y = (gy + 1.0f) * 128.0f - 0.5f;
            const float xf = floorf(x), yf = floorf(y);
            const float wx = x - xf, wy = y - yf;
            const int ix0 = (int)xf, iy0 = (int)yf;

            const u16* pb = planes + ((((size_t)(b * 3 + p)) << 16) << 5) + q * 8;

            auto corner = [&](int ix, int iy, float w) {
                const bool v = (ix >= 0) & (ix < WW) & (iy >= 0) & (iy < HH);
                w = v ? w : 0.f;
                const int ixc = min(max(ix, 0), WW - 1);
                const int iyc = min(max(iy, 0), HH - 1);
                const int yx = (iyc << 8) | ixc;
                const uint4 d = *(const uint4*)(pb + ((size_t)yx << 5));
#pragma unroll
                for (int j = 0; j < 4; ++j) {
                    const u32 u = (&d.x)[j];
                    const float lo = __uint_as_float(u << 16);
                    const float hi = __uint_as_float(u & 0xffff0000u);
                    acc[2 * j + 0] = fmaf(w, lo, acc[2 * j + 0]);
                    acc[2 * j + 1] = fmaf(w, hi, acc[2 * j + 1]);
                }
            };
            corner(ix0,     iy0,     (1.f - wx) * (1.f - wy));
            corner(ix0 + 1, iy0,     wx * (1.f - wy));
            corner(ix0,     iy0 + 1, (1.f - wx) * wy);
            corner(ix0 + 1, iy0 + 1, wx * wy);
        }

        float* dst = sFeat + pt * 33 + q * 8;
#pragma unroll
        for (int j = 0; j < 8; ++j) dst[j] = acc[j];
    }
    __syncthreads();

    // ---- Phase B: thread-per-point MLP, weights via uniform (scalar) loads ----
    float feat[CP];
#pragma unroll
    for (int c = 0; c < CP; ++c) feat[c] = sFeat[tid * 33 + c];

    float h0[HID];
#pragma unroll
    for (int j = 0; j < HID; ++j) h0[j] = b0[j];
    for (int k = 0; k < CP; ++k) {
        const float f = feat[k];
        const float4* row = (const float4*)(W0 + k * HID);
#pragma unroll
        for (int j4 = 0; j4 < HID / 4; ++j4) {
            const float4 w = row[j4];
            h0[4 * j4 + 0] = fmaf(f, w.x, h0[4 * j4 + 0]);
            h0[4 * j4 + 1] = fmaf(f, w.y, h0[4 * j4 + 1]);
            h0[4 * j4 + 2] = fmaf(f, w.z, h0[4 * j4 + 2]);
            h0[4 * j4 + 3] = fmaf(f, w.w, h0[4 * j4 + 3]);
        }
    }
#pragma unroll
    for (int j = 0; j < HID; ++j) h0[j] = (h0[j] >= 0.f) ? h0[j] : 0.01f * h0[j];

    float h1[HID];
#pragma unroll
    for (int j = 0; j < HID; ++j) h1[j] = b1[j];
    for (int k = 0; k < HID; ++k) {
        const float f = h0[k];
        const float4* row = (const float4*)(W1 + k * HID);
#pragma unroll
        for (int j4 = 0; j4 < HID / 4; ++j4) {
            const float4 w = row[j4];
            h1[4 * j4 + 0] = fmaf(f, w.x, h1[4 * j4 + 0]);
            h1[4 * j4 + 1] = fmaf(f, w.y, h1[4 * j4 + 1]);
            h1[4 * j4 + 2] = fmaf(f, w.z, h1[4 * j4 + 2]);
            h1[4 * j4 + 3] = fmaf(f, w.w, h1[4 * j4 + 3]);
        }
    }
#pragma unroll
    for (int j = 0; j < HID; ++j) h1[j] = (h1[j] >= 0.f) ? h1[j] : 0.01f * h1[j];

    float o[NOUT];
#pragma unroll
    for (int j = 0; j < NOUT; ++j) o[j] = b2[j];
    for (int k = 0; k < HID; ++k) {
        const float f = h1[k];
        const float* row = W2 + k * NOUT;
#pragma unroll
        for (int j = 0; j < NOUT; ++j) o[j] = fmaf(f, row[j], o[j]);
    }

    // stage outputs into own sFeat row (only this thread touched/reads it)
#pragma unroll
    for (int j = 0; j < NOUT; ++j) sFeat[tid * 33 + j] = o[j];
    __syncthreads();

    // coalesced block write: 256*33 = 8448 floats = 2112 float4
    float4* dst4 = (float4*)(out + (size_t)blockBase * NOUT);
    const float4* src4 = (const float4*)sFeat;
    for (int v = tid; v < (TILE * NOUT) / 4; v += 256) dst4[v] = src4[v];
}

// ---------------------------------------------------------------------------
// Fallback (ws too small): scalar gather from original layout + LDS weights.
// ---------------------------------------------------------------------------
__global__ __launch_bounds__(256) void fused_fallback_k(const float* __restrict__ planes,
                                                        const float* __restrict__ points,
                                                        const float* __restrict__ W0,
                                                        const float* __restrict__ b0,
                                                        const float* __restrict__ W1,
                                                        const float* __restrict__ b1,
                                                        const float* __restrict__ W2,
                                                        const float* __restrict__ b2,
                                                        float* __restrict__ out) {
    const int tid = threadIdx.x;
    const int pgl = blockIdx.x * 256 + tid;
    const int b = pgl >> 19;
    const float px = points[(size_t)pgl * 3 + 0];
    const float py = points[(size_t)pgl * 3 + 1];
    const float pz = points[(size_t)pgl * 3 + 2];

    float feat[CP];
#pragma unroll
    for (int c = 0; c < CP; ++c) feat[c] = 0.f;

#pragma unroll
    for (int p = 0; p < PLANES; ++p) {
        const float gx = (p == 2) ? py : px;
        const float gy = (p == 0) ? py : pz;
        const float x = (gx + 1.0f) * 128.0f - 0.5f;
        const float y = (gy + 1.0f) * 128.0f - 0.5f;
        const float xf = floorf(x), yf = floorf(y);
        const float wx = x - xf, wy = y - yf;
        const int ix0 = (int)xf, iy0 = (int)yf;
        const float* pb = planes + (((size_t)(b * 96 + p * 32)) << 16);
        auto corner = [&](int ix, int iy, float w) {
            const bool v = (ix >= 0) & (ix < WW) & (iy >= 0) & (iy < HH);
            w = v ? w : 0.f;
            const int ixc = min(max(ix, 0), WW - 1);
            const int iyc = min(max(iy, 0), HH - 1);
            const int yx = (iyc << 8) | ixc;
            const float* src = pb + yx;
#pragma unroll
            for (int c = 0; c < CP; ++c) feat[c] = fmaf(w, src[(size_t)c << 16], feat[c]);
        };
        corner(ix0,     iy0,     (1.f - wx) * (1.f - wy));
        corner(ix0 + 1, iy0,     wx * (1.f - wy));
        corner(ix0,     iy0 + 1, (1.f - wx) * wy);
        corner(ix0 + 1, iy0 + 1, wx * wy);
    }

    float h0[HID];
#pragma unroll
    for (int j = 0; j < HID; ++j) h0[j] = b0[j];
    for (int k = 0; k < CP; ++k) {
        const float f = feat[k];
#pragma unroll
        for (int j = 0; j < HID; ++j) h0[j] = fmaf(f, W0[k * HID + j], h0[j]);
    }
#pragma unroll
    for (int j = 0; j < HID; ++j) h0[j] = (h0[j] >= 0.f) ? h0[j] : 0.01f * h0[j];

    float h1[HID];
#pragma unroll
    for (int j = 0; j < HID; ++j) h1[j] = b1[j];
    for (int k = 0; k < HID; ++k) {
        const float f = h0[k];
#pragma unroll
        for (int j = 0; j < HID; ++j) h1[j] = fmaf(f, W1[k * HID + j], h1[j]);
    }
#pragma unroll
    for (int j = 0; j < HID; ++j) h1[j] = (h1[j] >= 0.f) ? h1[j] : 0.01f * h1[j];

    float o[NOUT];
#pragma unroll
    for (int j = 0; j < NOUT; ++j) o[j] = b2[j];
    for (int k = 0; k < HID; ++k) {
        const float f = h1[k];
#pragma unroll
        for (int j = 0; j < NOUT; ++j) o[j] = fmaf(f, W2[k * NOUT + j], o[j]);
    }
    float* op = out + (size_t)pgl * NOUT;
#pragma unroll
    for (int j = 0; j < NOUT; ++j) op[j] = o[j];
}

// ---------------------------------------------------------------------------
extern "C" void kernel_launch(void* const* d_in, const int* in_sizes, int n_in,
                              void* d_out, int out_size, void* d_ws, size_t ws_size,
                              hipStream_t stream) {
    const float* triplane = (const float*)d_in[0];
    const float* points   = (const float*)d_in[1];
    const float* W0 = (const float*)d_in[2];
    const float* b0 = (const float*)d_in[3];
    const float* W1 = (const float*)d_in[4];
    const float* b1 = (const float*)d_in[5];
    const float* W2 = (const float*)d_in[6];
    const float* b2 = (const float*)d_in[7];
    float* out = (float*)d_out;

    const size_t need = (size_t)BATCH * PLANES * HWSZ * CP * sizeof(u16); // 25.2 MB

    if (d_ws != nullptr && ws_size >= need) {
        u16* tws = (u16*)d_ws;
        transpose_bf16_k<<<(BATCH * PLANES * HWSZ) / 256, 256, 0, stream>>>(triplane, tws);
        fused2_k<<<NPTS_TOTAL / TILE, 256, 0, stream>>>(
            tws, points, W0, b0, W1, b1, W2, b2, out);
    } else {
        fused_fallback_k<<<NPTS_TOTAL / 256, 256, 0, stream>>>(
            triplane, points, W0, b0, W1, b1, W2, b2, out);
    }
}

// Round 3
// 400.727 us; speedup vs baseline: 3.3833x; 1.8142x over previous
//
#include <hip/hip_runtime.h>

// Problem constants
#define BATCH 2
#define PLANES 3
#define CP 32
#define HH 256
#define WW 256
#define HWSZ 65536
#define HID 64
#define NOUT 33
#define NPTS_TOTAL 1048576
#define PLANE_ELEMS 2097152      // HWSZ*CP (u16 elems per plane)
#define MPTS 128                 // points per mlp block

typedef unsigned int u32;
typedef unsigned short u16;
typedef float floatx4 __attribute__((ext_vector_type(4)));
typedef short bf16x8 __attribute__((ext_vector_type(8)));

static __device__ __forceinline__ u16 f2bf(float f) {
    u32 u = __float_as_uint(f);
    return (u16)((u + 0x7fffu + ((u >> 16) & 1u)) >> 16);  // RNE
}

// ---------------------------------------------------------------------------
// Kernel 1: transpose triplane (B, 96, H, W) fp32 -> ws (B*3, H*W, 32) bf16.
// ---------------------------------------------------------------------------
__global__ __launch_bounds__(256) void transpose_bf16_k(const float* __restrict__ tp,
                                                        u16* __restrict__ out) {
    int idx = blockIdx.x * 256 + threadIdx.x;
    int bp = idx >> 16;
    int yx = idx & 65535;
    int b = bp / 3, p = bp - 3 * b;
    const float* src = tp + (((size_t)(b * 96 + p * 32)) << 16) + yx;
    u16 v[32];
#pragma unroll
    for (int c = 0; c < 32; ++c) v[c] = f2bf(src[(size_t)c << 16]);
    uint4* dst = (uint4*)(out + ((size_t)idx << 5));
#pragma unroll
    for (int i = 0; i < 4; ++i) {
        uint4 w;
        w.x = (u32)v[8 * i + 0] | ((u32)v[8 * i + 1] << 16);
        w.y = (u32)v[8 * i + 2] | ((u32)v[8 * i + 3] << 16);
        w.z = (u32)v[8 * i + 4] | ((u32)v[8 * i + 5] << 16);
        w.w = (u32)v[8 * i + 6] | ((u32)v[8 * i + 7] << 16);
        dst[i] = w;
    }
}

// ---------------------------------------------------------------------------
// Kernel 2: gather only. task = (point, 8-ch chunk); no LDS -> high occupancy.
// Writes feats [pt][32] bf16 (wave writes 1024 contiguous B, coalesced).
// ---------------------------------------------------------------------------
__global__ __launch_bounds__(256) void gather_k(const u16* __restrict__ planes,
                                                const float* __restrict__ points,
                                                u16* __restrict__ feats) {
    const int task = blockIdx.x * 256 + threadIdx.x;  // < NPTS_TOTAL*4
    const int pt = task >> 2;
    const int q = task & 3;
    const int b = pt >> 19;
    const float px = points[(size_t)pt * 3 + 0];
    const float py = points[(size_t)pt * 3 + 1];
    const float pz = points[(size_t)pt * 3 + 2];

    float acc[8];
#pragma unroll
    for (int j = 0; j < 8; ++j) acc[j] = 0.f;

#pragma unroll
    for (int p = 0; p < PLANES; ++p) {
        const float gx = (p == 2) ? py : px;
        const float gy = (p == 0) ? py : pz;
        const float x = (gx + 1.0f) * 128.0f - 0.5f;
        const float y = (gy + 1.0f) * 128.0f - 0.5f;
        const float xf = floorf(x), yf = floorf(y);
        const float wx = x - xf, wy = y - yf;
        const int ix0 = (int)xf, iy0 = (int)yf;
        const u16* pb = planes + (size_t)(b * 3 + p) * PLANE_ELEMS + q * 8;

        auto corner = [&](int ix, int iy, float w) {
            const bool v = (ix >= 0) & (ix < WW) & (iy >= 0) & (iy < HH);
            w = v ? w : 0.f;
            const int ixc = min(max(ix, 0), WW - 1);
            const int iyc = min(max(iy, 0), HH - 1);
            const int yx = (iyc << 8) | ixc;
            const uint4 d = *(const uint4*)(pb + ((size_t)yx << 5));
#pragma unroll
            for (int j = 0; j < 4; ++j) {
                const u32 u = (&d.x)[j];
                acc[2 * j + 0] = fmaf(w, __uint_as_float(u << 16), acc[2 * j + 0]);
                acc[2 * j + 1] = fmaf(w, __uint_as_float(u & 0xffff0000u), acc[2 * j + 1]);
            }
        };
        corner(ix0,     iy0,     (1.f - wx) * (1.f - wy));
        corner(ix0 + 1, iy0,     wx * (1.f - wy));
        corner(ix0,     iy0 + 1, (1.f - wx) * wy);
        corner(ix0 + 1, iy0 + 1, wx * wy);
    }

    uint4 o;
    o.x = (u32)f2bf(acc[0]) | ((u32)f2bf(acc[1]) << 16);
    o.y = (u32)f2bf(acc[2]) | ((u32)f2bf(acc[3]) << 16);
    o.z = (u32)f2bf(acc[4]) | ((u32)f2bf(acc[5]) << 16);
    o.w = (u32)f2bf(acc[6]) | ((u32)f2bf(acc[7]) << 16);
    *(uint4*)(feats + (size_t)pt * 32 + q * 8) = o;
}

// ---------------------------------------------------------------------------
// Kernel 3: MFMA MLP. 128 points / 256-thread block (4 waves, 32 pts each).
// D[m][n] = sum_k Wt[m][k] * X[n][k] via mfma_f32_16x16x32_bf16.
// A-frag: A[m=lane&15][k=quad*8+j]; B-frag: B[k=quad*8+j][n=lane&15];
// C/D: col(lane&15)=n, row(quad*4+reg)=m.  [layouts per cdna4 guide §3]
// Padded LDS strides (40/72 elems) keep b128 reads conflict-free.
// ---------------------------------------------------------------------------
__global__ __launch_bounds__(256) void mlp_k(const u16* __restrict__ feats,
                                             const float* __restrict__ W0,
                                             const float* __restrict__ b0,
                                             const float* __restrict__ W1,
                                             const float* __restrict__ b1,
                                             const float* __restrict__ W2,
                                             const float* __restrict__ b2,
                                             float* __restrict__ out) {
    __shared__ __align__(16) u16 sW0t[64 * 40];   // Wt0[m][k], stride 40
    __shared__ __align__(16) u16 sW1t[64 * 72];   // Wt1[m][k], stride 72
    __shared__ __align__(16) u16 sW2t[48 * 72];   // Wt2[m][k] (m<33 valid)
    __shared__ __align__(16) u16 sR0[MPTS * 72];  // X0 (stride 40) then X2 (stride 72)
    __shared__ __align__(16) u16 sR1[MPTS * 72];  // X1 (stride 72) then sOut (fp32 stride 36)
    __shared__ float sB0[64], sB1[64], sB2[33];

    const int tid = threadIdx.x;
    for (int i = tid; i < 32 * 64; i += 256) { int k = i >> 6, m = i & 63; sW0t[m * 40 + k] = f2bf(W0[i]); }
    for (int i = tid; i < 64 * 64; i += 256) { int k = i >> 6, m = i & 63; sW1t[m * 72 + k] = f2bf(W1[i]); }
    for (int i = tid; i < 64 * 33; i += 256) { int k = i / 33, m = i - 33 * k; sW2t[m * 72 + k] = f2bf(W2[i]); }
    if (tid < 64) { sB0[tid] = b0[tid]; sB1[tid] = b1[tid]; }
    if (tid < 33) sB2[tid] = b2[tid];

    const size_t pbase = (size_t)blockIdx.x * MPTS;
    for (int i = tid; i < MPTS * 4; i += 256) {
        int pt = i >> 2, q = i & 3;
        uint4 d = *(const uint4*)(feats + (pbase + pt) * 32 + q * 8);
        *(uint4*)(sR0 + pt * 40 + q * 8) = d;
    }
    __syncthreads();

    const int lane = tid & 63, wv = tid >> 6;
    const int ln = lane & 15, qd = lane >> 4;

    // ---- layer 0: K=32, M=64 (4 tiles), 2 N-tiles per wave ----
    bf16x8 a0[4];
#pragma unroll
    for (int mt = 0; mt < 4; ++mt)
        a0[mt] = *(const bf16x8*)(sW0t + (mt * 16 + ln) * 40 + qd * 8);
    bf16x8 bx0[2];
#pragma unroll
    for (int nt = 0; nt < 2; ++nt)
        bx0[nt] = *(const bf16x8*)(sR0 + (wv * 32 + nt * 16 + ln) * 40 + qd * 8);
    floatx4 acc0[2][4];
#pragma unroll
    for (int nt = 0; nt < 2; ++nt)
#pragma unroll
        for (int mt = 0; mt < 4; ++mt) {
            floatx4 z = {0.f, 0.f, 0.f, 0.f};
            acc0[nt][mt] = __builtin_amdgcn_mfma_f32_16x16x32_bf16(a0[mt], bx0[nt], z, 0, 0, 0);
        }
    // epilogue 0 -> X1 (sR1, stride 72); rows are wave-private
#pragma unroll
    for (int nt = 0; nt < 2; ++nt) {
        const int n = wv * 32 + nt * 16 + ln;
#pragma unroll
        for (int mt = 0; mt < 4; ++mt) {
            u16 p[4];
#pragma unroll
            for (int r = 0; r < 4; ++r) {
                const int m = mt * 16 + qd * 4 + r;
                float v = acc0[nt][mt][r] + sB0[m];
                v = (v >= 0.f) ? v : 0.01f * v;
                p[r] = f2bf(v);
            }
            uint2 dd = make_uint2((u32)p[0] | ((u32)p[1] << 16), (u32)p[2] | ((u32)p[3] << 16));
            *(uint2*)(sR1 + n * 72 + mt * 16 + qd * 4) = dd;
        }
    }

    // ---- layer 1: K=64 (2 chunks) ----
    bf16x8 a1[4][2];
#pragma unroll
    for (int mt = 0; mt < 4; ++mt)
#pragma unroll
        for (int c = 0; c < 2; ++c)
            a1[mt][c] = *(const bf16x8*)(sW1t + (mt * 16 + ln) * 72 + c * 32 + qd * 8);
    floatx4 acc1[2][4];
#pragma unroll
    for (int nt = 0; nt < 2; ++nt) {
        const int n = wv * 32 + nt * 16 + ln;
        bf16x8 bf0 = *(const bf16x8*)(sR1 + n * 72 + qd * 8);
        bf16x8 bf1 = *(const bf16x8*)(sR1 + n * 72 + 32 + qd * 8);
#pragma unroll
        for (int mt = 0; mt < 4; ++mt) {
            floatx4 z = {0.f, 0.f, 0.f, 0.f};
            floatx4 t = __builtin_amdgcn_mfma_f32_16x16x32_bf16(a1[mt][0], bf0, z, 0, 0, 0);
            acc1[nt][mt] = __builtin_amdgcn_mfma_f32_16x16x32_bf16(a1[mt][1], bf1, t, 0, 0, 0);
        }
    }
    __syncthreads();  // all waves' X0 reads (sR0) done before X2 overwrites sR0

    // epilogue 1 -> X2 (sR0, stride 72)
#pragma unroll
    for (int nt = 0; nt < 2; ++nt) {
        const int n = wv * 32 + nt * 16 + ln;
#pragma unroll
        for (int mt = 0; mt < 4; ++mt) {
            u16 p[4];
#pragma unroll
            for (int r = 0; r < 4; ++r) {
                const int m = mt * 16 + qd * 4 + r;
                float v = acc1[nt][mt][r] + sB1[m];
                v = (v >= 0.f) ? v : 0.01f * v;
                p[r] = f2bf(v);
            }
            uint2 dd = make_uint2((u32)p[0] | ((u32)p[1] << 16), (u32)p[2] | ((u32)p[3] << 16));
            *(uint2*)(sR0 + n * 72 + mt * 16 + qd * 4) = dd;
        }
    }

    // ---- layer 2: K=64, M=48 (3 tiles; m<33 valid) ----
    bf16x8 a2[3][2];
#pragma unroll
    for (int mt = 0; mt < 3; ++mt)
#pragma unroll
        for (int c = 0; c < 2; ++c)
            a2[mt][c] = *(const bf16x8*)(sW2t + (mt * 16 + ln) * 72 + c * 32 + qd * 8);
    floatx4 acc2[2][3];
#pragma unroll
    for (int nt = 0; nt < 2; ++nt) {
        const int n = wv * 32 + nt * 16 + ln;
        bf16x8 bf0 = *(const bf16x8*)(sR0 + n * 72 + qd * 8);
        bf16x8 bf1 = *(const bf16x8*)(sR0 + n * 72 + 32 + qd * 8);
#pragma unroll
        for (int mt = 0; mt < 3; ++mt) {
            floatx4 z = {0.f, 0.f, 0.f, 0.f};
            floatx4 t = __builtin_amdgcn_mfma_f32_16x16x32_bf16(a2[mt][0], bf0, z, 0, 0, 0);
            acc2[nt][mt] = __builtin_amdgcn_mfma_f32_16x16x32_bf16(a2[mt][1], bf1, t, 0, 0, 0);
        }
    }
    __syncthreads();  // X1 reads done before sOut overlays sR1

    // epilogue 2 -> sOut fp32, stride 36 (row n overlays X1 row n: wave-private)
    float* sOut = (float*)sR1;
#pragma unroll
    for (int nt = 0; nt < 2; ++nt) {
        const int n = wv * 32 + nt * 16 + ln;
#pragma unroll
        for (int mt = 0; mt < 3; ++mt)
#pragma unroll
            for (int r = 0; r < 4; ++r) {
                const int m = mt * 16 + qd * 4 + r;
                if (m < NOUT) sOut[n * 36 + m] = acc2[nt][mt][r] + sB2[m];
            }
    }
    __syncthreads();

    // coalesced copy out: MPTS*33 floats
    float* og = out + pbase * NOUT;
    for (int i = tid; i < MPTS * NOUT; i += 256) {
        int n = i / 33, m = i - 33 * n;
        og[i] = sOut[n * 36 + m];
    }
}

// ---------------------------------------------------------------------------
// Fallback paths (smaller ws): round-2 fused kernel; no-ws scalar kernel.
// ---------------------------------------------------------------------------
__global__ __launch_bounds__(256) void fused2_k(const u16* __restrict__ planes,
                                                const float* __restrict__ points,
                                                const float* __restrict__ W0,
                                                const float* __restrict__ b0,
                                                const float* __restrict__ W1,
                                                const float* __restrict__ b1,
                                                const float* __restrict__ W2,
                                                const float* __restrict__ b2,
                                                float* __restrict__ out) {
    __shared__ __align__(16) float sPts[256 * 3];
    __shared__ __align__(16) float sFeat[256 * 33];
    const int tid = threadIdx.x;
    const int blockBase = blockIdx.x * 256;
    const int b = blockIdx.x >> 11;
    const float* psrc = points + (size_t)blockBase * 3;
#pragma unroll
    for (int i = 0; i < 3; ++i) sPts[tid + 256 * i] = psrc[tid + 256 * i];
    __syncthreads();
#pragma unroll
    for (int i = 0; i < 4; ++i) {
        const int task = i * 256 + tid;
        const int pt = task >> 2, q = task & 3;
        const float px = sPts[pt * 3 + 0], py = sPts[pt * 3 + 1], pz = sPts[pt * 3 + 2];
        float acc[8];
#pragma unroll
        for (int j = 0; j < 8; ++j) acc[j] = 0.f;
#pragma unroll
        for (int p = 0; p < PLANES; ++p) {
            const float gx = (p == 2) ? py : px;
            const float gy = (p == 0) ? py : pz;
            const float x = (gx + 1.0f) * 128.0f - 0.5f;
            const float y = (gy + 1.0f) * 128.0f - 0.5f;
            const float xf = floorf(x), yf = floorf(y);
            const float wx = x - xf, wy = y - yf;
            const int ix0 = (int)xf, iy0 = (int)yf;
            const u16* pb = planes + (size_t)(b * 3 + p) * PLANE_ELEMS + q * 8;
            auto corner = [&](int ix, int iy, float w) {
                const bool v = (ix >= 0) & (ix < WW) & (iy >= 0) & (iy < HH);
                w = v ? w : 0.f;
                const int ixc = min(max(ix, 0), WW - 1);
                const int iyc = min(max(iy, 0), HH - 1);
                const int yx = (iyc << 8) | ixc;
                const uint4 d = *(const uint4*)(pb + ((size_t)yx << 5));
#pragma unroll
                for (int j = 0; j < 4; ++j) {
                    const u32 u = (&d.x)[j];
                    acc[2 * j + 0] = fmaf(w, __uint_as_float(u << 16), acc[2 * j + 0]);
                    acc[2 * j + 1] = fmaf(w, __uint_as_float(u & 0xffff0000u), acc[2 * j + 1]);
                }
            };
            corner(ix0,     iy0,     (1.f - wx) * (1.f - wy));
            corner(ix0 + 1, iy0,     wx * (1.f - wy));
            corner(ix0,     iy0 + 1, (1.f - wx) * wy);
            corner(ix0 + 1, iy0 + 1, wx * wy);
        }
        float* dst = sFeat + pt * 33 + q * 8;
#pragma unroll
        for (int j = 0; j < 8; ++j) dst[j] = acc[j];
    }
    __syncthreads();
    float feat[CP];
#pragma unroll
    for (int c = 0; c < CP; ++c) feat[c] = sFeat[tid * 33 + c];
    float h0[HID];
#pragma unroll
    for (int j = 0; j < HID; ++j) h0[j] = b0[j];
    for (int k = 0; k < CP; ++k) {
        const float f = feat[k];
        const float4* row = (const float4*)(W0 + k * HID);
#pragma unroll
        for (int j4 = 0; j4 < HID / 4; ++j4) {
            const float4 w = row[j4];
            h0[4 * j4 + 0] = fmaf(f, w.x, h0[4 * j4 + 0]);
            h0[4 * j4 + 1] = fmaf(f, w.y, h0[4 * j4 + 1]);
            h0[4 * j4 + 2] = fmaf(f, w.z, h0[4 * j4 + 2]);
            h0[4 * j4 + 3] = fmaf(f, w.w, h0[4 * j4 + 3]);
        }
    }
#pragma unroll
    for (int j = 0; j < HID; ++j) h0[j] = (h0[j] >= 0.f) ? h0[j] : 0.01f * h0[j];
    float h1[HID];
#pragma unroll
    for (int j = 0; j < HID; ++j) h1[j] = b1[j];
    for (int k = 0; k < HID; ++k) {
        const float f = h0[k];
        const float4* row = (const float4*)(W1 + k * HID);
#pragma unroll
        for (int j4 = 0; j4 < HID / 4; ++j4) {
            const float4 w = row[j4];
            h1[4 * j4 + 0] = fmaf(f, w.x, h1[4 * j4 + 0]);
            h1[4 * j4 + 1] = fmaf(f, w.y, h1[4 * j4 + 1]);
            h1[4 * j4 + 2] = fmaf(f, w.z, h1[4 * j4 + 2]);
            h1[4 * j4 + 3] = fmaf(f, w.w, h1[4 * j4 + 3]);
        }
    }
#pragma unroll
    for (int j = 0; j < HID; ++j) h1[j] = (h1[j] >= 0.f) ? h1[j] : 0.01f * h1[j];
    float o[NOUT];
#pragma unroll
    for (int j = 0; j < NOUT; ++j) o[j] = b2[j];
    for (int k = 0; k < HID; ++k) {
        const float f = h1[k];
        const float* row = W2 + k * NOUT;
#pragma unroll
        for (int j = 0; j < NOUT; ++j) o[j] = fmaf(f, row[j], o[j]);
    }
#pragma unroll
    for (int j = 0; j < NOUT; ++j) sFeat[tid * 33 + j] = o[j];
    __syncthreads();
    float4* dst4 = (float4*)(out + (size_t)blockBase * NOUT);
    const float4* src4 = (const float4*)sFeat;
    for (int v = tid; v < (256 * NOUT) / 4; v += 256) dst4[v] = src4[v];
}

__global__ __launch_bounds__(256) void fused_fallback_k(const float* __restrict__ planes,
                                                        const float* __restrict__ points,
                                                        const float* __restrict__ W0,
                                                        const float* __restrict__ b0,
                                                        const float* __restrict__ W1,
                                                        const float* __restrict__ b1,
                                                        const float* __restrict__ W2,
                                                        const float* __restrict__ b2,
                                                        float* __restrict__ out) {
    const int tid = threadIdx.x;
    const int pgl = blockIdx.x * 256 + tid;
    const int b = pgl >> 19;
    const float px = points[(size_t)pgl * 3 + 0];
    const float py = points[(size_t)pgl * 3 + 1];
    const float pz = points[(size_t)pgl * 3 + 2];
    float feat[CP];
#pragma unroll
    for (int c = 0; c < CP; ++c) feat[c] = 0.f;
#pragma unroll
    for (int p = 0; p < PLANES; ++p) {
        const float gx = (p == 2) ? py : px;
        const float gy = (p == 0) ? py : pz;
        const float x = (gx + 1.0f) * 128.0f - 0.5f;
        const float y = (gy + 1.0f) * 128.0f - 0.5f;
        const float xf = floorf(x), yf = floorf(y);
        const float wx = x - xf, wy = y - yf;
        const int ix0 = (int)xf, iy0 = (int)yf;
        const float* pb = planes + (((size_t)(b * 96 + p * 32)) << 16);
        auto corner = [&](int ix, int iy, float w) {
            const bool v = (ix >= 0) & (ix < WW) & (iy >= 0) & (iy < HH);
            w = v ? w : 0.f;
            const int ixc = min(max(ix, 0), WW - 1);
            const int iyc = min(max(iy, 0), HH - 1);
            const int yx = (iyc << 8) | ixc;
            const float* src = pb + yx;
#pragma unroll
            for (int c = 0; c < CP; ++c) feat[c] = fmaf(w, src[(size_t)c << 16], feat[c]);
        };
        corner(ix0,     iy0,     (1.f - wx) * (1.f - wy));
        corner(ix0 + 1, iy0,     wx * (1.f - wy));
        corner(ix0,     iy0 + 1, (1.f - wx) * wy);
        corner(ix0 + 1, iy0 + 1, wx * wy);
    }
    float h0[HID];
#pragma unroll
    for (int j = 0; j < HID; ++j) h0[j] = b0[j];
    for (int k = 0; k < CP; ++k) {
        const float f = feat[k];
#pragma unroll
        for (int j = 0; j < HID; ++j) h0[j] = fmaf(f, W0[k * HID + j], h0[j]);
    }
#pragma unroll
    for (int j = 0; j < HID; ++j) h0[j] = (h0[j] >= 0.f) ? h0[j] : 0.01f * h0[j];
    float h1[HID];
#pragma unroll
    for (int j = 0; j < HID; ++j) h1[j] = b1[j];
    for (int k = 0; k < HID; ++k) {
        const float f = h0[k];
#pragma unroll
        for (int j = 0; j < HID; ++j) h1[j] = fmaf(f, W1[k * HID + j], h1[j]);
    }
#pragma unroll
    for (int j = 0; j < HID; ++j) h1[j] = (h1[j] >= 0.f) ? h1[j] : 0.01f * h1[j];
    float o[NOUT];
#pragma unroll
    for (int j = 0; j < NOUT; ++j) o[j] = b2[j];
    for (int k = 0; k < HID; ++k) {
        const float f = h1[k];
#pragma unroll
        for (int j = 0; j < NOUT; ++j) o[j] = fmaf(f, W2[k * NOUT + j], o[j]);
    }
    float* op = out + (size_t)pgl * NOUT;
#pragma unroll
    for (int j = 0; j < NOUT; ++j) op[j] = o[j];
}

// ---------------------------------------------------------------------------
extern "C" void kernel_launch(void* const* d_in, const int* in_sizes, int n_in,
                              void* d_out, int out_size, void* d_ws, size_t ws_size,
                              hipStream_t stream) {
    const float* triplane = (const float*)d_in[0];
    const float* points   = (const float*)d_in[1];
    const float* W0 = (const float*)d_in[2];
    const float* b0 = (const float*)d_in[3];
    const float* W1 = (const float*)d_in[4];
    const float* b1 = (const float*)d_in[5];
    const float* W2 = (const float*)d_in[6];
    const float* b2 = (const float*)d_in[7];
    float* out = (float*)d_out;

    const size_t needPlanes = (size_t)BATCH * PLANES * PLANE_ELEMS * sizeof(u16); // 25.2 MB
    const size_t needFeats  = (size_t)NPTS_TOTAL * 32 * sizeof(u16);              // 67.1 MB

    if (d_ws != nullptr && ws_size >= needPlanes + needFeats) {
        u16* planesW = (u16*)d_ws;
        u16* featsW  = planesW + (size_t)BATCH * PLANES * PLANE_ELEMS;
        transpose_bf16_k<<<(BATCH * PLANES * HWSZ) / 256, 256, 0, stream>>>(triplane, planesW);
        gather_k<<<(NPTS_TOTAL * 4) / 256, 256, 0, stream>>>(planesW, points, featsW);
        mlp_k<<<NPTS_TOTAL / MPTS, 256, 0, stream>>>(featsW, W0, b0, W1, b1, W2, b2, out);
    } else if (d_ws != nullptr && ws_size >= needPlanes) {
        u16* planesW = (u16*)d_ws;
        transpose_bf16_k<<<(BATCH * PLANES * HWSZ) / 256, 256, 0, stream>>>(triplane, planesW);
        fused2_k<<<NPTS_TOTAL / 256, 256, 0, stream>>>(planesW, points, W0, b0, W1, b1, W2, b2, out);
    } else {
        fused_fallback_k<<<NPTS_TOTAL / 256, 256, 0, stream>>>(
            triplane, points, W0, b0, W1, b1, W2, b2, out);
    }
}